// Round 2
// baseline (263.561 us; speedup 1.0000x reference)
//
#include <hip/hip_runtime.h>
#include <hip/hip_bf16.h>

// ---------------- types & helpers ----------------
typedef short bf16x8 __attribute__((ext_vector_type(8)));
typedef float f32x4  __attribute__((ext_vector_type(4)));
typedef unsigned short u16x4 __attribute__((ext_vector_type(4)));

#define CDIM   768
#define NQKV   2304
#define MROWS  8192
#define TSEQ   2048
#define HD     64
#define NHEAD  12
#define BHTOT  48

__device__ __forceinline__ unsigned short f2bf(float f) {
    unsigned int x;
    __builtin_memcpy(&x, &f, 4);
    unsigned int r = (x + 0x7fffu + ((x >> 16) & 1u)) >> 16;
    return (unsigned short)r;
}

__device__ __forceinline__ f32x4 mfma16(bf16x8 a, bf16x8 b, f32x4 c) {
    return __builtin_amdgcn_mfma_f32_16x16x32_bf16(a, b, c, 0, 0, 0);
}

// async global->LDS, 16B per lane, LDS dest = wave-uniform base + lane*16
__device__ __forceinline__ void gl_lds16(const unsigned short* g, unsigned short* l) {
    __builtin_amdgcn_global_load_lds(
        (__attribute__((address_space(1))) void*)(g),
        (__attribute__((address_space(3))) void*)(l),
        16, 0, 0);
}

// ---------------- kernel A: X fp32 -> bf16 ----------------
__global__ __launch_bounds__(256) void convert_x(
    const float* __restrict__ X, unsigned short* __restrict__ Xb)
{
    size_t i = ((size_t)blockIdx.x * 256 + threadIdx.x) * 4;
    f32x4 v = *(const f32x4*)(X + i);
    u16x4 o;
#pragma unroll
    for (int j = 0; j < 4; j++) o[j] = f2bf(v[j]);
    *(u16x4*)(Xb + i) = o;
}

// ---------------- kernel B: W fp32 (768x2304) -> Wt bf16 (2304x768) ----------------
__global__ __launch_bounds__(256) void transpose_w(
    const float* __restrict__ W, unsigned short* __restrict__ Wt)
{
    __shared__ __align__(16) unsigned short tile[64][72];
    const int bx = blockIdx.x;  // n-tile (36)
    const int by = blockIdx.y;  // k-tile (12)
    const int tid = threadIdx.x;
#pragma unroll
    for (int c = 0; c < 4; c++) {
        int chunk = tid + 256 * c;            // [0,1024)
        int r = chunk >> 4, cc = chunk & 15;  // r = k-local row, cc = 4-col chunk
        f32x4 v = *(const f32x4*)(W + (size_t)(by * 64 + r) * NQKV + bx * 64 + cc * 4);
#pragma unroll
        for (int j = 0; j < 4; j++) tile[cc * 4 + j][r] = f2bf(v[j]);
    }
    __syncthreads();
#pragma unroll
    for (int c = 0; c < 2; c++) {
        int chunk = tid + 256 * c;
        int r = chunk >> 3, cc = chunk & 7;  // r = n-local row, cc = 8-k chunk
        bf16x8 v;
#pragma unroll
        for (int j = 0; j < 8; j++) v[j] = (short)tile[r][cc * 8 + j];
        *(bf16x8*)(Wt + (size_t)(bx * 64 + r) * CDIM + by * 64 + cc * 8) = v;
    }
}

// ---------------- kernel 1: QKV GEMM + bias, scatter to Q / K / V^T ----------------
// C[m][n] = sum_k Xb[m][k] * Wt[n][k] + bias[n]
#define BM 128
#define BN 128
#define BK 32

__global__ __launch_bounds__(256, 2) void qkv_gemm(
    const unsigned short* __restrict__ X,    // (8192, 768) bf16
    const unsigned short* __restrict__ Wt,   // (2304, 768) bf16
    const float* __restrict__ Bias,          // (2304) fp32
    unsigned short* __restrict__ Q,          // (48, 2048, 64)
    unsigned short* __restrict__ Km,         // (48, 2048, 64)
    unsigned short* __restrict__ Vt)         // (48, 64, 2048)
{
    __shared__ __align__(16) unsigned short As[BM * BK];  // 8 KB
    __shared__ __align__(16) unsigned short Bs[BN * BK];  // 8 KB
    const int tid  = threadIdx.x;
    const int wave = tid >> 6, lane = tid & 63;
    const int quad = lane >> 4, m16 = lane & 15;
    const int wr = wave >> 1, wc = wave & 1;
    const int m0 = blockIdx.y * BM, n0 = blockIdx.x * BN;

    f32x4 acc[4][4];
#pragma unroll
    for (int i = 0; i < 4; i++)
#pragma unroll
        for (int j = 0; j < 4; j++) acc[i][j] = f32x4{0.f, 0.f, 0.f, 0.f};

    const unsigned short* xb = X + (size_t)m0 * CDIM;
    const unsigned short* wb = Wt + (size_t)n0 * CDIM;

    for (int k0 = 0; k0 < CDIM; k0 += BK) {
#pragma unroll
        for (int c = 0; c < 2; c++) {
            int e = wave * 1024 + c * 512 + lane * 8;
            int m = e >> 5, kk = e & 31;
            gl_lds16(xb + (size_t)m * CDIM + k0 + kk, As + wave * 1024 + c * 512);
            gl_lds16(wb + (size_t)m * CDIM + k0 + kk, Bs + wave * 1024 + c * 512);
        }
        __syncthreads();
        bf16x8 af[4], bfg[4];
#pragma unroll
        for (int t = 0; t < 4; t++) {
            af[t]  = *(const bf16x8*)(As + (wr * 64 + t * 16 + m16) * BK + quad * 8);
            bfg[t] = *(const bf16x8*)(Bs + (wc * 64 + t * 16 + m16) * BK + quad * 8);
        }
#pragma unroll
        for (int i = 0; i < 4; i++)
#pragma unroll
            for (int j = 0; j < 4; j++)
                acc[i][j] = mfma16(af[i], bfg[j], acc[i][j]);
        __syncthreads();
    }

    // epilogue: bias + scatter. Block lies entirely in one of q/k/v (768 = 6*128).
    const int region = n0 / CDIM;
#pragma unroll
    for (int i = 0; i < 4; i++) {
        int row = m0 + wr * 64 + i * 16 + quad * 4;
#pragma unroll
        for (int j = 0; j < 4; j++) {
            int gcol = n0 + wc * 64 + j * 16 + m16;
            int cc = gcol - region * CDIM;
            int h = cc >> 6, d = cc & 63;
            float bv = Bias[gcol];
#pragma unroll
            for (int r = 0; r < 4; r++) {
                int gm = row + r;
                int b = gm >> 11, t = gm & 2047;
                int bh = b * NHEAD + h;
                unsigned short o = f2bf(acc[i][j][r] + bv);
                if (region == 0)      Q[((size_t)bh * TSEQ + t) * HD + d] = o;
                else if (region == 1) Km[((size_t)bh * TSEQ + t) * HD + d] = o;
                else                  Vt[((size_t)bh * HD + d) * TSEQ + t] = o;
            }
        }
    }
}

// ---------------- kernel 2: causal relu-attention ----------------
// per (bh, 128-row q tile): O = relu_causal(Q K^T * 0.125) @ V
#define BI 128
#define BJ 128
#define LDP 136  // P row stride (bf16): 272 B

__global__ __launch_bounds__(256, 2) void attn(
    const unsigned short* __restrict__ Q,
    const unsigned short* __restrict__ Kmat,
    const unsigned short* __restrict__ Vt,
    float* __restrict__ Out)
{
    // KP: first 128*64 elems used as K tile; whole buffer reused as P (128 x LDP)
    __shared__ __align__(16) unsigned short KP[BI * LDP];  // 34816 B
    __shared__ __align__(16) unsigned short VTs[HD * BJ];  // 16384 B

    const int tid  = threadIdx.x;
    const int wave = tid >> 6, lane = tid & 63;
    const int quad = lane >> 4, m16 = lane & 15;
    const int wr = wave >> 1, wc = wave & 1;
    const int bh = blockIdx.x >> 4;
    const int it = 15 - (blockIdx.x & 15);  // heavy diagonal blocks first
    const int i0 = it * BI;

    const unsigned short* qb = Q    + (size_t)bh * TSEQ * HD;
    const unsigned short* kb = Kmat + (size_t)bh * TSEQ * HD;
    const unsigned short* vb = Vt   + (size_t)bh * HD * TSEQ;

    // register-resident Q fragments (loop-invariant)
    bf16x8 qf[4][2];
#pragma unroll
    for (int ti = 0; ti < 4; ti++)
#pragma unroll
        for (int ks = 0; ks < 2; ks++)
            qf[ti][ks] = *(const bf16x8*)(qb + (size_t)(i0 + wr * 64 + ti * 16 + m16) * HD +
                                          ks * 32 + quad * 8);

    f32x4 oacc[4][2];
#pragma unroll
    for (int i = 0; i < 4; i++)
#pragma unroll
        for (int j = 0; j < 2; j++) oacc[i][j] = f32x4{0.f, 0.f, 0.f, 0.f};

    for (int jt = 0; jt <= it; jt++) {
        const int j0 = jt * BJ;
        // stage K tile (128x64) into KP[0:8192], V^T tile (64x128) into VTs
#pragma unroll
        for (int c = 0; c < 4; c++) {
            int e = wave * 2048 + c * 512 + lane * 8;
            int r = e >> 6, d = e & 63;
            gl_lds16(kb + (size_t)(j0 + r) * HD + d, KP + wave * 2048 + c * 512);
            int dv = e >> 7, jj = e & 127;
            gl_lds16(vb + (size_t)dv * TSEQ + j0 + jj, VTs + wave * 2048 + c * 512);
        }
        __syncthreads();

        // S = Q K^T  (wave computes 64x64)
        f32x4 sacc[4][4];
#pragma unroll
        for (int i = 0; i < 4; i++)
#pragma unroll
            for (int j = 0; j < 4; j++) sacc[i][j] = f32x4{0.f, 0.f, 0.f, 0.f};
        bf16x8 kf[4][2];
#pragma unroll
        for (int tj = 0; tj < 4; tj++)
#pragma unroll
            for (int ks = 0; ks < 2; ks++)
                kf[tj][ks] = *(const bf16x8*)(KP + (wc * 64 + tj * 16 + m16) * HD +
                                              ks * 32 + quad * 8);
#pragma unroll
        for (int ks = 0; ks < 2; ks++)
#pragma unroll
            for (int ti = 0; ti < 4; ti++)
#pragma unroll
                for (int tj = 0; tj < 4; tj++)
                    sacc[ti][tj] = mfma16(qf[ti][ks], kf[tj][ks], sacc[ti][tj]);
        __syncthreads();  // all waves done reading K before P overwrites it

        // scale + relu + causal mask -> P (bf16) in LDS
#pragma unroll
        for (int ti = 0; ti < 4; ti++) {
            int ri = wr * 64 + ti * 16 + quad * 4;
#pragma unroll
            for (int tj = 0; tj < 4; tj++) {
                int cj = wc * 64 + tj * 16 + m16;
                int gj = j0 + cj;
#pragma unroll
                for (int r = 0; r < 4; r++) {
                    int gi = i0 + ri + r;
                    float v = sacc[ti][tj][r] * 0.125f;
                    v = (v > 0.f && gj <= gi) ? v : 0.f;
                    KP[(ri + r) * LDP + cj] = f2bf(v);
                }
            }
        }
        __syncthreads();

        // O += P @ V  (wave computes 64x32)
#pragma unroll
        for (int kk = 0; kk < 4; kk++) {
            bf16x8 pf[4], vf[2];
#pragma unroll
            for (int ti = 0; ti < 4; ti++)
                pf[ti] = *(const bf16x8*)(KP + (wr * 64 + ti * 16 + m16) * LDP +
                                          kk * 32 + quad * 8);
#pragma unroll
            for (int tj = 0; tj < 2; tj++)
                vf[tj] = *(const bf16x8*)(VTs + (wc * 32 + tj * 16 + m16) * BJ +
                                          kk * 32 + quad * 8);
#pragma unroll
            for (int ti = 0; ti < 4; ti++)
#pragma unroll
                for (int tj = 0; tj < 2; tj++)
                    oacc[ti][tj] = mfma16(pf[ti], vf[tj], oacc[ti][tj]);
        }
        __syncthreads();  // P/V reads done before next iter's staging
    }

    // epilogue: O -> out (B, T, C) fp32
    const int b = bh / NHEAD, h = bh % NHEAD;
#pragma unroll
    for (int ti = 0; ti < 4; ti++) {
        int ri = i0 + wr * 64 + ti * 16 + quad * 4;
#pragma unroll
        for (int tj = 0; tj < 2; tj++) {
            int d = wc * 32 + tj * 16 + m16;
#pragma unroll
            for (int r = 0; r < 4; r++) {
                int t = ri + r;
                Out[((size_t)b * TSEQ + t) * CDIM + h * HD + d] = oacc[ti][tj][r];
            }
        }
    }
}

// ---------------- launch ----------------
extern "C" void kernel_launch(void* const* d_in, const int* in_sizes, int n_in,
                              void* d_out, int out_size, void* d_ws, size_t ws_size,
                              hipStream_t stream) {
    const float* X    = (const float*)d_in[0];  // (4,2048,768) fp32
    const float* W    = (const float*)d_in[1];  // (768,2304) fp32
    const float* Bias = (const float*)d_in[2];  // (2304) fp32
    float* out = (float*)d_out;

    unsigned short* Xb = (unsigned short*)d_ws;            // 8192*768
    unsigned short* Wt = Xb + (size_t)MROWS * CDIM;        // 2304*768
    unsigned short* Q  = Wt + (size_t)NQKV * CDIM;         // 48*2048*64
    unsigned short* Km = Q  + (size_t)BHTOT * TSEQ * HD;
    unsigned short* Vt = Km + (size_t)BHTOT * TSEQ * HD;

    hipLaunchKernelGGL(convert_x, dim3((MROWS * CDIM) / 1024), dim3(256), 0, stream, X, Xb);
    hipLaunchKernelGGL(transpose_w, dim3(NQKV / 64, CDIM / 64), dim3(256), 0, stream, W, Wt);
    hipLaunchKernelGGL(qkv_gemm, dim3(NQKV / BN, MROWS / BM), dim3(256), 0, stream,
                       X /*unused*/ == nullptr ? Xb : Xb, Wt, Bias, Q, Km, Vt);
    hipLaunchKernelGGL(attn, dim3(BHTOT * 16), dim3(256), 0, stream, Q, Km, Vt, out);
}

// Round 3
// 200.475 us; speedup vs baseline: 1.3147x; 1.3147x over previous
//
#include <hip/hip_runtime.h>
#include <hip/hip_bf16.h>

// ---------------- types & helpers ----------------
typedef short bf16x8 __attribute__((ext_vector_type(8)));
typedef float f32x4  __attribute__((ext_vector_type(4)));
typedef unsigned short u16x4 __attribute__((ext_vector_type(4)));

#define CDIM   768
#define NQKV   2304
#define MROWS  8192
#define TSEQ   2048
#define HD     64
#define NHEAD  12
#define BHTOT  48

__device__ __forceinline__ unsigned short f2bf(float f) {
    unsigned int x;
    __builtin_memcpy(&x, &f, 4);
    unsigned int r = (x + 0x7fffu + ((x >> 16) & 1u)) >> 16;
    return (unsigned short)r;
}

// pack two f32 -> bf16 pair (a -> low, b -> high), round-to-nearest (+0.5 ulp)
__device__ __forceinline__ unsigned int pkbf(float a, float b) {
    unsigned int ua, ub;
    __builtin_memcpy(&ua, &a, 4);
    __builtin_memcpy(&ub, &b, 4);
    return __builtin_amdgcn_perm(ua + 0x8000u, ub + 0x8000u, 0x03020706u);
}

__device__ __forceinline__ f32x4 mfma16(bf16x8 a, bf16x8 b, f32x4 c) {
    return __builtin_amdgcn_mfma_f32_16x16x32_bf16(a, b, c, 0, 0, 0);
}

// async global->LDS, 16B per lane, LDS dest = wave-uniform base + lane*16
__device__ __forceinline__ void gl_lds16(const unsigned short* g, unsigned short* l) {
    __builtin_amdgcn_global_load_lds(
        (__attribute__((address_space(1))) void*)(g),
        (__attribute__((address_space(3))) void*)(l),
        16, 0, 0);
}

// ---------------- kernel A: X fp32 -> bf16 ----------------
__global__ __launch_bounds__(256) void convert_x(
    const float* __restrict__ X, unsigned short* __restrict__ Xb)
{
    size_t i = ((size_t)blockIdx.x * 256 + threadIdx.x) * 4;
    f32x4 v = *(const f32x4*)(X + i);
    u16x4 o;
#pragma unroll
    for (int j = 0; j < 4; j++) o[j] = f2bf(v[j]);
    *(u16x4*)(Xb + i) = o;
}

// ---------------- kernel B: W fp32 (768x2304) -> Wt bf16 (2304x768) ----------------
__global__ __launch_bounds__(256) void transpose_w(
    const float* __restrict__ W, unsigned short* __restrict__ Wt)
{
    __shared__ __align__(16) unsigned short tile[64][72];
    const int bx = blockIdx.x;  // n-tile (36)
    const int by = blockIdx.y;  // k-tile (12)
    const int tid = threadIdx.x;
#pragma unroll
    for (int c = 0; c < 4; c++) {
        int chunk = tid + 256 * c;            // [0,1024)
        int r = chunk >> 4, cc = chunk & 15;
        f32x4 v = *(const f32x4*)(W + (size_t)(by * 64 + r) * NQKV + bx * 64 + cc * 4);
#pragma unroll
        for (int j = 0; j < 4; j++) tile[cc * 4 + j][r] = f2bf(v[j]);
    }
    __syncthreads();
#pragma unroll
    for (int c = 0; c < 2; c++) {
        int chunk = tid + 256 * c;
        int r = chunk >> 3, cc = chunk & 7;
        bf16x8 v;
#pragma unroll
        for (int j = 0; j < 8; j++) v[j] = (short)tile[r][cc * 8 + j];
        *(bf16x8*)(Wt + (size_t)(bx * 64 + r) * CDIM + by * 64 + cc * 8) = v;
    }
}

// ---------------- kernel 1: QKV GEMM + bias, scatter to Q / K / V^T ----------------
// Q additionally pre-scaled by 0.125 (attention scale folded in).
#define BM 128
#define BN 128
#define BK 32

__global__ __launch_bounds__(256, 2) void qkv_gemm(
    const unsigned short* __restrict__ X,    // (8192, 768) bf16
    const unsigned short* __restrict__ Wt,   // (2304, 768) bf16
    const float* __restrict__ Bias,          // (2304) fp32
    unsigned short* __restrict__ Q,          // (48, 2048, 64)  pre-scaled by 1/8
    unsigned short* __restrict__ Km,         // (48, 2048, 64)
    unsigned short* __restrict__ Vt)         // (48, 64, 2048)
{
    __shared__ __align__(16) unsigned short As[BM * BK];
    __shared__ __align__(16) unsigned short Bs[BN * BK];
    const int tid  = threadIdx.x;
    const int wave = tid >> 6, lane = tid & 63;
    const int quad = lane >> 4, m16 = lane & 15;
    const int wr = wave >> 1, wc = wave & 1;
    const int m0 = blockIdx.y * BM, n0 = blockIdx.x * BN;

    f32x4 acc[4][4];
#pragma unroll
    for (int i = 0; i < 4; i++)
#pragma unroll
        for (int j = 0; j < 4; j++) acc[i][j] = f32x4{0.f, 0.f, 0.f, 0.f};

    const unsigned short* xb = X + (size_t)m0 * CDIM;
    const unsigned short* wb = Wt + (size_t)n0 * CDIM;

    for (int k0 = 0; k0 < CDIM; k0 += BK) {
#pragma unroll
        for (int c = 0; c < 2; c++) {
            int e = wave * 1024 + c * 512 + lane * 8;
            int m = e >> 5, kk = e & 31;
            gl_lds16(xb + (size_t)m * CDIM + k0 + kk, As + wave * 1024 + c * 512);
            gl_lds16(wb + (size_t)m * CDIM + k0 + kk, Bs + wave * 1024 + c * 512);
        }
        __syncthreads();
        bf16x8 af[4], bfg[4];
#pragma unroll
        for (int t = 0; t < 4; t++) {
            af[t]  = *(const bf16x8*)(As + (wr * 64 + t * 16 + m16) * BK + quad * 8);
            bfg[t] = *(const bf16x8*)(Bs + (wc * 64 + t * 16 + m16) * BK + quad * 8);
        }
#pragma unroll
        for (int i = 0; i < 4; i++)
#pragma unroll
            for (int j = 0; j < 4; j++)
                acc[i][j] = mfma16(af[i], bfg[j], acc[i][j]);
        __syncthreads();
    }

    const int region = n0 / CDIM;
    const float qscale = (region == 0) ? 0.125f : 1.0f;
#pragma unroll
    for (int i = 0; i < 4; i++) {
        int row = m0 + wr * 64 + i * 16 + quad * 4;
#pragma unroll
        for (int j = 0; j < 4; j++) {
            int gcol = n0 + wc * 64 + j * 16 + m16;
            int cc = gcol - region * CDIM;
            int h = cc >> 6, d = cc & 63;
            float bv = Bias[gcol];
#pragma unroll
            for (int r = 0; r < 4; r++) {
                int gm = row + r;
                int b = gm >> 11, t = gm & 2047;
                int bh = b * NHEAD + h;
                unsigned short o = f2bf((acc[i][j][r] + bv) * qscale);
                if (region == 0)      Q[((size_t)bh * TSEQ + t) * HD + d] = o;
                else if (region == 1) Km[((size_t)bh * TSEQ + t) * HD + d] = o;
                else                  Vt[((size_t)bh * HD + d) * TSEQ + t] = o;
            }
        }
    }
}

// ---------------- kernel 2: causal relu-attention (S^T formulation) ----------------
// Per (bh, 128-row q tile). Wave w owns O rows i in [w*32, w*32+32).
// S^T = K(permuted-j-rows) @ Q^T computed in C-layout, which directly equals the
// A-operand layout of P for the PV mfma (j-rowmap {0-3,8-11,16-19,24-27}/{4-7,...}).
// K/V LDS tiles use a parity XOR swizzle on 16B chunks (applied at DMA-source
// side) so all ds_read_b128 are bank-balanced. 2 barriers per j-iter, no P LDS.
#define LDSK 0
#define LDSV 8192

__global__ __launch_bounds__(256, 3) void attn(
    const unsigned short* __restrict__ Q,
    const unsigned short* __restrict__ Kmat,
    const unsigned short* __restrict__ Vt,
    float* __restrict__ Out)
{
    __shared__ __align__(16) unsigned short S[16384];  // K 16KB | V 16KB

    const int tid  = threadIdx.x;
    const int wave = tid >> 6, lane = tid & 63;
    const int q4 = lane >> 4, m16 = lane & 15;
    const int q8 = m16 >> 2, m3 = m16 & 3;
    const int par = (m3 ^ (m3 >> 1)) & 1;  // parity of low 2 bits

    const int bh = blockIdx.x >> 4;
    const int it = 15 - (blockIdx.x & 15);  // heavy diagonal blocks first
    const int i0 = it * 128;

    const unsigned short* qb = Q    + (size_t)bh * TSEQ * HD;
    const unsigned short* kb = Kmat + (size_t)bh * TSEQ * HD;
    const unsigned short* vb = Vt   + (size_t)bh * HD * TSEQ;

    // Q fragments (B-operand), loop-invariant: i = i0 + wave*32 + si*16 + m16
    bf16x8 qf[2][2];
#pragma unroll
    for (int si = 0; si < 2; si++)
#pragma unroll
        for (int ks = 0; ks < 2; ks++)
            qf[si][ks] = *(const bf16x8*)(qb +
                (size_t)(i0 + wave * 32 + si * 16 + m16) * HD + ks * 32 + q4 * 8);

    f32x4 oacc[2][4];
#pragma unroll
    for (int si = 0; si < 2; si++)
#pragma unroll
        for (int dn = 0; dn < 4; dn++) oacc[si][dn] = f32x4{0.f, 0.f, 0.f, 0.f};

    // precomputed LDS read bases (u16 units)
    const int kbase0 = q8 * 512 + m3 * 64 + q4 * 8 + par * 32;        // ks^par==par
    const int kbase1 = q8 * 512 + m3 * 64 + q4 * 8 + 32 - par * 32;   // ks^par==1-par
    const int vbase0 = m16 * 128 + q4 * 8 + par * 32;                 // kk even
    const int vbase1 = m16 * 128 + q4 * 8 + 32 - par * 32;            // kk odd

    for (int jt = 0; jt <= it; jt++) {
        const int j0 = jt * 128;
        // ---- stage K (128x64) and V^T (64x128), swizzled chunks ----
#pragma unroll
        for (int cc = 0; cc < 4; cc++) {
            int cs = wave * 4 + cc;
            {   // K: 8 chunks (16B) per row
                int s = cs * 64 + lane;
                int row = s >> 3, ch = s & 7;
                int c = ch ^ (((row ^ (row >> 1)) & 1) * 4);
                gl_lds16(kb + (size_t)(j0 + row) * HD + c * 8, &S[LDSK] + cs * 512);
            }
            {   // V: 16 chunks per row
                int s = cs * 64 + lane;
                int d = s >> 4, ch = s & 15;
                int c = ch ^ (((d ^ (d >> 1)) & 1) * 4);
                gl_lds16(vb + (size_t)d * TSEQ + j0 + c * 8, &S[LDSV] + cs * 512);
            }
        }
        __syncthreads();

        const bool diag = (jt == it);
#pragma unroll
        for (int kk = 0; kk < 4; kk++) {
            // S^T subtile pair (su = 2kk, 2kk+1): j rows = kk*32 + permuted map
            bf16x8 kf_e0 = *(const bf16x8*)(&S[LDSK] + kbase0 + kk * 2048);
            bf16x8 kf_e1 = *(const bf16x8*)(&S[LDSK] + kbase1 + kk * 2048);
            bf16x8 kf_o0 = *(const bf16x8*)(&S[LDSK] + kbase0 + kk * 2048 + 256);
            bf16x8 kf_o1 = *(const bf16x8*)(&S[LDSK] + kbase1 + kk * 2048 + 256);

            f32x4 sacc[2][2];  // [odd][si]
#pragma unroll
            for (int o = 0; o < 2; o++)
#pragma unroll
                for (int si = 0; si < 2; si++) sacc[o][si] = f32x4{0.f, 0.f, 0.f, 0.f};
#pragma unroll
            for (int si = 0; si < 2; si++) {
                sacc[0][si] = mfma16(kf_e0, qf[si][0], sacc[0][si]);
                sacc[0][si] = mfma16(kf_e1, qf[si][1], sacc[0][si]);
                sacc[1][si] = mfma16(kf_o0, qf[si][0], sacc[1][si]);
                sacc[1][si] = mfma16(kf_o1, qf[si][1], sacc[1][si]);
            }

            // relu (+causal mask on diagonal tile) + pack to bf16 pairs
            unsigned int pk[2][2][2];  // [odd][si][pair]
#pragma unroll
            for (int o = 0; o < 2; o++)
#pragma unroll
                for (int si = 0; si < 2; si++) {
                    f32x4 v = sacc[o][si];
                    if (diag) {
#pragma unroll
                        for (int r = 0; r < 4; r++) {
                            int gj = kk * 32 + q4 * 8 + o * 4 + r;
                            int gi = wave * 32 + si * 16 + m16;
                            if (gj > gi) v[r] = 0.f;
                        }
                    }
#pragma unroll
                    for (int r = 0; r < 4; r++) v[r] = fmaxf(v[r], 0.f);
                    pk[o][si][0] = pkbf(v[0], v[1]);
                    pk[o][si][1] = pkbf(v[2], v[3]);
                }

            // O += P @ V for this k-chunk (j = kk*32..kk*32+31)
#pragma unroll
            for (int dn = 0; dn < 4; dn++) {
                const int vb_off = ((kk & 1) ? vbase1 : vbase0) + (kk >> 1) * 64 + dn * 2048;
                bf16x8 vf = *(const bf16x8*)(&S[LDSV] + vb_off);
#pragma unroll
                for (int si = 0; si < 2; si++) {
                    union { bf16x8 v; unsigned int u[4]; } af;
                    af.u[0] = pk[0][si][0];
                    af.u[1] = pk[0][si][1];
                    af.u[2] = pk[1][si][0];
                    af.u[3] = pk[1][si][1];
                    oacc[si][dn] = mfma16(af.v, vf, oacc[si][dn]);
                }
            }
        }
        __syncthreads();  // all LDS reads done before next iter's DMA overwrite
    }

    // epilogue: O (i = i0+wave*32+si*16+q4*4+r, d = dn*16+m16) -> out fp32
    const int b = bh / NHEAD, h = bh % NHEAD;
#pragma unroll
    for (int si = 0; si < 2; si++) {
        int ri = i0 + wave * 32 + si * 16 + q4 * 4;
#pragma unroll
        for (int dn = 0; dn < 4; dn++) {
            int d = dn * 16 + m16;
#pragma unroll
            for (int r = 0; r < 4; r++) {
                Out[((size_t)b * TSEQ + ri + r) * CDIM + h * HD + d] = oacc[si][dn][r];
            }
        }
    }
}

// ---------------- launch ----------------
extern "C" void kernel_launch(void* const* d_in, const int* in_sizes, int n_in,
                              void* d_out, int out_size, void* d_ws, size_t ws_size,
                              hipStream_t stream) {
    const float* X    = (const float*)d_in[0];  // (4,2048,768) fp32
    const float* W    = (const float*)d_in[1];  // (768,2304) fp32
    const float* Bias = (const float*)d_in[2];  // (2304) fp32
    float* out = (float*)d_out;

    unsigned short* Xb = (unsigned short*)d_ws;
    unsigned short* Wt = Xb + (size_t)MROWS * CDIM;
    unsigned short* Q  = Wt + (size_t)NQKV * CDIM;
    unsigned short* Km = Q  + (size_t)BHTOT * TSEQ * HD;
    unsigned short* Vt = Km + (size_t)BHTOT * TSEQ * HD;

    hipLaunchKernelGGL(convert_x, dim3((MROWS * CDIM) / 1024), dim3(256), 0, stream, X, Xb);
    hipLaunchKernelGGL(transpose_w, dim3(NQKV / 64, CDIM / 64), dim3(256), 0, stream, W, Wt);
    hipLaunchKernelGGL(qkv_gemm, dim3(NQKV / BN, MROWS / BM), dim3(256), 0, stream,
                       Xb, Wt, Bias, Q, Km, Vt);
    hipLaunchKernelGGL(attn, dim3(BHTOT * 16), dim3(256), 0, stream, Q, Km, Vt, out);
}

// Round 4
// 194.159 us; speedup vs baseline: 1.3574x; 1.0325x over previous
//
#include <hip/hip_runtime.h>
#include <hip/hip_bf16.h>

// ---------------- types & helpers ----------------
typedef short bf16x8 __attribute__((ext_vector_type(8)));
typedef float f32x4  __attribute__((ext_vector_type(4)));
typedef unsigned short u16x4 __attribute__((ext_vector_type(4)));

#define CDIM   768
#define NQKV   2304
#define MROWS  8192
#define TSEQ   2048
#define HD     64
#define NHEAD  12
#define BHTOT  48

__device__ __forceinline__ unsigned short f2bf(float f) {
    unsigned int x;
    __builtin_memcpy(&x, &f, 4);
    unsigned int r = (x + 0x7fffu + ((x >> 16) & 1u)) >> 16;
    return (unsigned short)r;
}

// pack two f32 -> bf16 pair (a -> low, b -> high)
__device__ __forceinline__ unsigned int pkbf(float a, float b) {
    unsigned int ua, ub;
    __builtin_memcpy(&ua, &a, 4);
    __builtin_memcpy(&ub, &b, 4);
    return __builtin_amdgcn_perm(ua + 0x8000u, ub + 0x8000u, 0x03020706u);
}

__device__ __forceinline__ f32x4 mfma16(bf16x8 a, bf16x8 b, f32x4 c) {
    return __builtin_amdgcn_mfma_f32_16x16x32_bf16(a, b, c, 0, 0, 0);
}

// async global->LDS, 16B per lane, LDS dest = wave-uniform base + lane*16
__device__ __forceinline__ void gl_lds16(const unsigned short* g, unsigned short* l) {
    __builtin_amdgcn_global_load_lds(
        (__attribute__((address_space(1))) void*)(g),
        (__attribute__((address_space(3))) void*)(l),
        16, 0, 0);
}

// ---------------- kernel A: X fp32 -> bf16 ----------------
__global__ __launch_bounds__(256) void convert_x(
    const float* __restrict__ X, unsigned short* __restrict__ Xb)
{
    size_t i = ((size_t)blockIdx.x * 256 + threadIdx.x) * 4;
    f32x4 v = *(const f32x4*)(X + i);
    u16x4 o;
#pragma unroll
    for (int j = 0; j < 4; j++) o[j] = f2bf(v[j]);
    *(u16x4*)(Xb + i) = o;
}

// ---------------- kernel B: W fp32 (768x2304) -> Wt bf16 (2304x768) ----------------
__global__ __launch_bounds__(256) void transpose_w(
    const float* __restrict__ W, unsigned short* __restrict__ Wt)
{
    __shared__ __align__(16) unsigned short tile[64][72];
    const int bx = blockIdx.x;  // n-tile (36)
    const int by = blockIdx.y;  // k-tile (12)
    const int tid = threadIdx.x;
#pragma unroll
    for (int c = 0; c < 4; c++) {
        int chunk = tid + 256 * c;
        int r = chunk >> 4, cc = chunk & 15;
        f32x4 v = *(const f32x4*)(W + (size_t)(by * 64 + r) * NQKV + bx * 64 + cc * 4);
#pragma unroll
        for (int j = 0; j < 4; j++) tile[cc * 4 + j][r] = f2bf(v[j]);
    }
    __syncthreads();
#pragma unroll
    for (int c = 0; c < 2; c++) {
        int chunk = tid + 256 * c;
        int r = chunk >> 3, cc = chunk & 7;
        bf16x8 v;
#pragma unroll
        for (int j = 0; j < 8; j++) v[j] = (short)tile[r][cc * 8 + j];
        *(bf16x8*)(Wt + (size_t)(bx * 64 + r) * CDIM + by * 64 + cc * 8) = v;
    }
}

// ---------------- kernel 1: QKV GEMM + bias, scatter to Q / K / V^T ----------------
// BK=64, XOR-swizzled LDS (chunk pos = ch ^ (row&7)) -> conflict-free b128 reads.
// Q pre-scaled by 0.125.
#define BM 128
#define BN 128
#define BK 64

__global__ __launch_bounds__(256, 4) void qkv_gemm(
    const unsigned short* __restrict__ X,    // (8192, 768) bf16
    const unsigned short* __restrict__ Wt,   // (2304, 768) bf16
    const float* __restrict__ Bias,          // (2304) fp32
    unsigned short* __restrict__ Q,          // (48, 2048, 64)  pre-scaled 1/8
    unsigned short* __restrict__ Km,         // (48, 2048, 64)
    unsigned short* __restrict__ Vt)         // (48, 64, 2048)
{
    __shared__ __align__(16) unsigned short As[BM * BK];  // 16 KB
    __shared__ __align__(16) unsigned short Bs[BN * BK];  // 16 KB
    const int tid  = threadIdx.x;
    const int wave = tid >> 6, lane = tid & 63;
    const int quad = lane >> 4, m16 = lane & 15;
    const int wr = wave >> 1, wc = wave & 1;
    const int m0 = blockIdx.y * BM, n0 = blockIdx.x * BN;

    f32x4 acc[4][4];
#pragma unroll
    for (int i = 0; i < 4; i++)
#pragma unroll
        for (int j = 0; j < 4; j++) acc[i][j] = f32x4{0.f, 0.f, 0.f, 0.f};

    const unsigned short* xb = X + (size_t)m0 * CDIM;
    const unsigned short* wb = Wt + (size_t)n0 * CDIM;

    // DMA slot map: slot s -> row = s>>3, pos = s&7, src chunk = pos ^ (row&7)
    const int srow[4] = {  // per-call row/chunk for this lane (call c: base wave*256+c*64)
        (wave * 256 + 0 * 64 + lane) >> 3, (wave * 256 + 1 * 64 + lane) >> 3,
        (wave * 256 + 2 * 64 + lane) >> 3, (wave * 256 + 3 * 64 + lane) >> 3 };
    const int spos = lane & 7;

    // frag read offsets (u16 units): row*64 + (ch ^ (m16&7))*8
    const int rb = m16 & 7;

    for (int k0 = 0; k0 < CDIM; k0 += BK) {
#pragma unroll
        for (int c = 0; c < 4; c++) {
            int row = srow[c];
            int ch = spos ^ (row & 7);
            gl_lds16(xb + (size_t)row * CDIM + k0 + ch * 8, As + wave * 2048 + c * 512);
            gl_lds16(wb + (size_t)row * CDIM + k0 + ch * 8, Bs + wave * 2048 + c * 512);
        }
        __syncthreads();
#pragma unroll
        for (int ks = 0; ks < 2; ks++) {
            bf16x8 af[4], bfg[4];
#pragma unroll
            for (int t = 0; t < 4; t++) {
                int rowa = wr * 64 + t * 16 + m16;
                int rowb = wc * 64 + t * 16 + m16;
                int pos = (ks * 4 + quad) ^ rb;
                af[t]  = *(const bf16x8*)(As + rowa * 64 + pos * 8);
                bfg[t] = *(const bf16x8*)(Bs + rowb * 64 + pos * 8);
            }
#pragma unroll
            for (int i = 0; i < 4; i++)
#pragma unroll
                for (int j = 0; j < 4; j++)
                    acc[i][j] = mfma16(af[i], bfg[j], acc[i][j]);
        }
        __syncthreads();
    }

    const int region = n0 / CDIM;
    const float qscale = (region == 0) ? 0.125f : 1.0f;
#pragma unroll
    for (int i = 0; i < 4; i++) {
        int row = m0 + wr * 64 + i * 16 + quad * 4;
#pragma unroll
        for (int j = 0; j < 4; j++) {
            int gcol = n0 + wc * 64 + j * 16 + m16;
            int cc = gcol - region * CDIM;
            int h = cc >> 6, d = cc & 63;
            float bv = Bias[gcol];
#pragma unroll
            for (int r = 0; r < 4; r++) {
                int gm = row + r;
                int b = gm >> 11, t = gm & 2047;
                int bh = b * NHEAD + h;
                unsigned short o = f2bf((acc[i][j][r] + bv) * qscale);
                if (region == 0)      Q[((size_t)bh * TSEQ + t) * HD + d] = o;
                else if (region == 1) Km[((size_t)bh * TSEQ + t) * HD + d] = o;
                else                  Vt[((size_t)bh * HD + d) * TSEQ + t] = o;
            }
        }
    }
}

// ---------------- kernel 2: causal relu-attention (S^T formulation) ----------------
#define LDSK 0
#define LDSV 8192

__global__ __launch_bounds__(256, 4) void attn(
    const unsigned short* __restrict__ Q,
    const unsigned short* __restrict__ Kmat,
    const unsigned short* __restrict__ Vt,
    float* __restrict__ Out)
{
    __shared__ __align__(16) unsigned short S[16384];  // K 16KB | V 16KB

    const int tid  = threadIdx.x;
    const int wave = tid >> 6, lane = tid & 63;
    const int q4 = lane >> 4, m16 = lane & 15;
    const int q8 = m16 >> 2, m3 = m16 & 3;
    const int par = (m3 ^ (m3 >> 1)) & 1;

    const int bh = blockIdx.x >> 4;
    const int it = 15 - (blockIdx.x & 15);  // heavy diagonal blocks first
    const int i0 = it * 128;

    const unsigned short* qb = Q    + (size_t)bh * TSEQ * HD;
    const unsigned short* kb = Kmat + (size_t)bh * TSEQ * HD;
    const unsigned short* vb = Vt   + (size_t)bh * HD * TSEQ;

    bf16x8 qf[2][2];
#pragma unroll
    for (int si = 0; si < 2; si++)
#pragma unroll
        for (int ks = 0; ks < 2; ks++)
            qf[si][ks] = *(const bf16x8*)(qb +
                (size_t)(i0 + wave * 32 + si * 16 + m16) * HD + ks * 32 + q4 * 8);

    f32x4 oacc[2][4];
#pragma unroll
    for (int si = 0; si < 2; si++)
#pragma unroll
        for (int dn = 0; dn < 4; dn++) oacc[si][dn] = f32x4{0.f, 0.f, 0.f, 0.f};

    const int kbase0 = q8 * 512 + m3 * 64 + q4 * 8 + par * 32;
    const int kbase1 = q8 * 512 + m3 * 64 + q4 * 8 + 32 - par * 32;
    const int vbase0 = m16 * 128 + q4 * 8 + par * 32;
    const int vbase1 = m16 * 128 + q4 * 8 + 32 - par * 32;

    for (int jt = 0; jt <= it; jt++) {
        const int j0 = jt * 128;
#pragma unroll
        for (int cc = 0; cc < 4; cc++) {
            int cs = wave * 4 + cc;
            {
                int s = cs * 64 + lane;
                int row = s >> 3, ch = s & 7;
                int c = ch ^ (((row ^ (row >> 1)) & 1) * 4);
                gl_lds16(kb + (size_t)(j0 + row) * HD + c * 8, &S[LDSK] + cs * 512);
            }
            {
                int s = cs * 64 + lane;
                int d = s >> 4, ch = s & 15;
                int c = ch ^ (((d ^ (d >> 1)) & 1) * 4);
                gl_lds16(vb + (size_t)d * TSEQ + j0 + c * 8, &S[LDSV] + cs * 512);
            }
        }
        __syncthreads();

        const bool diag = (jt == it);
#pragma unroll
        for (int kk = 0; kk < 4; kk++) {
            bf16x8 kf_e0 = *(const bf16x8*)(&S[LDSK] + kbase0 + kk * 2048);
            bf16x8 kf_e1 = *(const bf16x8*)(&S[LDSK] + kbase1 + kk * 2048);
            bf16x8 kf_o0 = *(const bf16x8*)(&S[LDSK] + kbase0 + kk * 2048 + 256);
            bf16x8 kf_o1 = *(const bf16x8*)(&S[LDSK] + kbase1 + kk * 2048 + 256);

            f32x4 sacc[2][2];
#pragma unroll
            for (int o = 0; o < 2; o++)
#pragma unroll
                for (int si = 0; si < 2; si++) sacc[o][si] = f32x4{0.f, 0.f, 0.f, 0.f};
#pragma unroll
            for (int si = 0; si < 2; si++) {
                sacc[0][si] = mfma16(kf_e0, qf[si][0], sacc[0][si]);
                sacc[0][si] = mfma16(kf_e1, qf[si][1], sacc[0][si]);
                sacc[1][si] = mfma16(kf_o0, qf[si][0], sacc[1][si]);
                sacc[1][si] = mfma16(kf_o1, qf[si][1], sacc[1][si]);
            }

            unsigned int pk[2][2][2];
#pragma unroll
            for (int o = 0; o < 2; o++)
#pragma unroll
                for (int si = 0; si < 2; si++) {
                    f32x4 v = sacc[o][si];
                    if (diag) {
#pragma unroll
                        for (int r = 0; r < 4; r++) {
                            int gj = kk * 32 + q4 * 8 + o * 4 + r;
                            int gi = wave * 32 + si * 16 + m16;
                            if (gj > gi) v[r] = 0.f;
                        }
                    }
#pragma unroll
                    for (int r = 0; r < 4; r++) v[r] = fmaxf(v[r], 0.f);
                    pk[o][si][0] = pkbf(v[0], v[1]);
                    pk[o][si][1] = pkbf(v[2], v[3]);
                }

#pragma unroll
            for (int dn = 0; dn < 4; dn++) {
                const int vb_off = ((kk & 1) ? vbase1 : vbase0) + (kk >> 1) * 64 + dn * 2048;
                bf16x8 vf = *(const bf16x8*)(&S[LDSV] + vb_off);
#pragma unroll
                for (int si = 0; si < 2; si++) {
                    union { bf16x8 v; unsigned int u[4]; } af;
                    af.u[0] = pk[0][si][0];
                    af.u[1] = pk[0][si][1];
                    af.u[2] = pk[1][si][0];
                    af.u[3] = pk[1][si][1];
                    oacc[si][dn] = mfma16(af.v, vf, oacc[si][dn]);
                }
            }
        }
        __syncthreads();
    }

    const int b = bh / NHEAD, h = bh % NHEAD;
#pragma unroll
    for (int si = 0; si < 2; si++) {
        int ri = i0 + wave * 32 + si * 16 + q4 * 4;
#pragma unroll
        for (int dn = 0; dn < 4; dn++) {
            int d = dn * 16 + m16;
#pragma unroll
            for (int r = 0; r < 4; r++) {
                Out[((size_t)b * TSEQ + ri + r) * CDIM + h * HD + d] = oacc[si][dn][r];
            }
        }
    }
}

// ---------------- launch ----------------
extern "C" void kernel_launch(void* const* d_in, const int* in_sizes, int n_in,
                              void* d_out, int out_size, void* d_ws, size_t ws_size,
                              hipStream_t stream) {
    const float* X    = (const float*)d_in[0];
    const float* W    = (const float*)d_in[1];
    const float* Bias = (const float*)d_in[2];
    float* out = (float*)d_out;

    unsigned short* Xb = (unsigned short*)d_ws;
    unsigned short* Wt = Xb + (size_t)MROWS * CDIM;
    unsigned short* Q  = Wt + (size_t)NQKV * CDIM;
    unsigned short* Km = Q  + (size_t)BHTOT * TSEQ * HD;
    unsigned short* Vt = Km + (size_t)BHTOT * TSEQ * HD;

    hipLaunchKernelGGL(convert_x, dim3((MROWS * CDIM) / 1024), dim3(256), 0, stream, X, Xb);
    hipLaunchKernelGGL(transpose_w, dim3(NQKV / 64, CDIM / 64), dim3(256), 0, stream, W, Wt);
    hipLaunchKernelGGL(qkv_gemm, dim3(NQKV / BN, MROWS / BM), dim3(256), 0, stream,
                       Xb, Wt, Bias, Q, Km, Vt);
    hipLaunchKernelGGL(attn, dim3(BHTOT * 16), dim3(256), 0, stream, Q, Km, Vt, out);
}

// Round 5
// 182.071 us; speedup vs baseline: 1.4476x; 1.0664x over previous
//
#include <hip/hip_runtime.h>
#include <hip/hip_bf16.h>

// ---------------- types & helpers ----------------
typedef short bf16x8 __attribute__((ext_vector_type(8)));
typedef float f32x4  __attribute__((ext_vector_type(4)));
typedef unsigned short u16x4 __attribute__((ext_vector_type(4)));

#define CDIM   768
#define NQKV   2304
#define MROWS  8192
#define TSEQ   2048
#define HD     64
#define NHEAD  12
#define BHTOT  48

__device__ __forceinline__ unsigned short f2bf(float f) {
    unsigned int x;
    __builtin_memcpy(&x, &f, 4);
    unsigned int r = (x + 0x7fffu + ((x >> 16) & 1u)) >> 16;
    return (unsigned short)r;
}

// pack two f32 -> bf16 pair (a -> low, b -> high)
__device__ __forceinline__ unsigned int pkbf(float a, float b) {
    unsigned int ua, ub;
    __builtin_memcpy(&ua, &a, 4);
    __builtin_memcpy(&ub, &b, 4);
    return __builtin_amdgcn_perm(ua + 0x8000u, ub + 0x8000u, 0x03020706u);
}

__device__ __forceinline__ f32x4 mfma16(bf16x8 a, bf16x8 b, f32x4 c) {
    return __builtin_amdgcn_mfma_f32_16x16x32_bf16(a, b, c, 0, 0, 0);
}

// async global->LDS, 16B per lane, LDS dest = wave-uniform base + lane*16
__device__ __forceinline__ void gl_lds16(const unsigned short* g, unsigned short* l) {
    __builtin_amdgcn_global_load_lds(
        (__attribute__((address_space(1))) void*)(g),
        (__attribute__((address_space(3))) void*)(l),
        16, 0, 0);
}

// ---------------- kernel A: X fp32 -> bf16 ----------------
__global__ __launch_bounds__(256) void convert_x(
    const float* __restrict__ X, unsigned short* __restrict__ Xb)
{
    size_t i = ((size_t)blockIdx.x * 256 + threadIdx.x) * 4;
    f32x4 v = *(const f32x4*)(X + i);
    u16x4 o;
#pragma unroll
    for (int j = 0; j < 4; j++) o[j] = f2bf(v[j]);
    *(u16x4*)(Xb + i) = o;
}

// ---------------- kernel B: W fp32 (768x2304) -> Wt bf16 (2304x768) ----------------
__global__ __launch_bounds__(256) void transpose_w(
    const float* __restrict__ W, unsigned short* __restrict__ Wt)
{
    __shared__ __align__(16) unsigned short tile[64][72];
    const int bx = blockIdx.x;
    const int by = blockIdx.y;
    const int tid = threadIdx.x;
#pragma unroll
    for (int c = 0; c < 4; c++) {
        int chunk = tid + 256 * c;
        int r = chunk >> 4, cc = chunk & 15;
        f32x4 v = *(const f32x4*)(W + (size_t)(by * 64 + r) * NQKV + bx * 64 + cc * 4);
#pragma unroll
        for (int j = 0; j < 4; j++) tile[cc * 4 + j][r] = f2bf(v[j]);
    }
    __syncthreads();
#pragma unroll
    for (int c = 0; c < 2; c++) {
        int chunk = tid + 256 * c;
        int r = chunk >> 3, cc = chunk & 7;
        bf16x8 v;
#pragma unroll
        for (int j = 0; j < 8; j++) v[j] = (short)tile[r][cc * 8 + j];
        *(bf16x8*)(Wt + (size_t)(bx * 64 + r) * CDIM + by * 64 + cc * 8) = v;
    }
}

// ---------------- kernel 1: QKV GEMM + bias, scatter to Q / K / V^T ----------------
#define BM 128
#define BN 128
#define BK 64

__global__ __launch_bounds__(256, 4) void qkv_gemm(
    const unsigned short* __restrict__ X,
    const unsigned short* __restrict__ Wt,
    const float* __restrict__ Bias,
    unsigned short* __restrict__ Q,          // pre-scaled 1/8
    unsigned short* __restrict__ Km,
    unsigned short* __restrict__ Vt)
{
    __shared__ __align__(16) unsigned short As[BM * BK];
    __shared__ __align__(16) unsigned short Bs[BN * BK];
    const int tid  = threadIdx.x;
    const int wave = tid >> 6, lane = tid & 63;
    const int quad = lane >> 4, m16 = lane & 15;
    const int wr = wave >> 1, wc = wave & 1;
    const int m0 = blockIdx.y * BM, n0 = blockIdx.x * BN;

    f32x4 acc[4][4];
#pragma unroll
    for (int i = 0; i < 4; i++)
#pragma unroll
        for (int j = 0; j < 4; j++) acc[i][j] = f32x4{0.f, 0.f, 0.f, 0.f};

    const unsigned short* xb = X + (size_t)m0 * CDIM;
    const unsigned short* wb = Wt + (size_t)n0 * CDIM;

    const int srow[4] = {
        (wave * 256 + 0 * 64 + lane) >> 3, (wave * 256 + 1 * 64 + lane) >> 3,
        (wave * 256 + 2 * 64 + lane) >> 3, (wave * 256 + 3 * 64 + lane) >> 3 };
    const int spos = lane & 7;
    const int rb = m16 & 7;

    for (int k0 = 0; k0 < CDIM; k0 += BK) {
#pragma unroll
        for (int c = 0; c < 4; c++) {
            int row = srow[c];
            int ch = spos ^ (row & 7);
            gl_lds16(xb + (size_t)row * CDIM + k0 + ch * 8, As + wave * 2048 + c * 512);
            gl_lds16(wb + (size_t)row * CDIM + k0 + ch * 8, Bs + wave * 2048 + c * 512);
        }
        __syncthreads();
#pragma unroll
        for (int ks = 0; ks < 2; ks++) {
            bf16x8 af[4], bfg[4];
#pragma unroll
            for (int t = 0; t < 4; t++) {
                int rowa = wr * 64 + t * 16 + m16;
                int rowb = wc * 64 + t * 16 + m16;
                int pos = (ks * 4 + quad) ^ rb;
                af[t]  = *(const bf16x8*)(As + rowa * 64 + pos * 8);
                bfg[t] = *(const bf16x8*)(Bs + rowb * 64 + pos * 8);
            }
#pragma unroll
            for (int i = 0; i < 4; i++)
#pragma unroll
                for (int j = 0; j < 4; j++)
                    acc[i][j] = mfma16(af[i], bfg[j], acc[i][j]);
        }
        __syncthreads();
    }

    const int region = n0 / CDIM;
    const float qscale = (region == 0) ? 0.125f : 1.0f;
#pragma unroll
    for (int i = 0; i < 4; i++) {
        int row = m0 + wr * 64 + i * 16 + quad * 4;
#pragma unroll
        for (int j = 0; j < 4; j++) {
            int gcol = n0 + wc * 64 + j * 16 + m16;
            int cc = gcol - region * CDIM;
            int h = cc >> 6, d = cc & 63;
            float bv = Bias[gcol];
#pragma unroll
            for (int r = 0; r < 4; r++) {
                int gm = row + r;
                int b = gm >> 11, t = gm & 2047;
                int bh = b * NHEAD + h;
                unsigned short o = f2bf((acc[i][j][r] + bv) * qscale);
                if (region == 0)      Q[((size_t)bh * TSEQ + t) * HD + d] = o;
                else if (region == 1) Km[((size_t)bh * TSEQ + t) * HD + d] = o;
                else                  Vt[((size_t)bh * HD + d) * TSEQ + t] = o;
            }
        }
    }
}

// ---------------- kernel 2: causal relu-attention (S^T formulation) ----------------
// K LDS layout: chunk idx = row*8 + (ch ^ (((row>>3&1)<<2)|(row&3)))
// V LDS layout: chunk idx = d*16 + (ch ^ (d&7) on low-3 bits)
// Both make every ds_read_b128 a per-8-lane-group bijection over idx&7 -> conflict-free.
#define LDSK 0
#define LDSV 8192

__global__ __launch_bounds__(256, 4) void attn(
    const unsigned short* __restrict__ Q,
    const unsigned short* __restrict__ Kmat,
    const unsigned short* __restrict__ Vt,
    float* __restrict__ Out)
{
    __shared__ __align__(16) unsigned short S[16384];  // K 16KB | V 16KB

    const int tid  = threadIdx.x;
    const int wave = tid >> 6, lane = tid & 63;
    const int q4 = lane >> 4, m16 = lane & 15;
    const int q8 = m16 >> 2, m3 = m16 & 3;

    // XCD-aware mapping: same-bh blocks share an XCD's L2; heavy diagonals first.
    const int xcd = blockIdx.x & 7;
    const int idx = blockIdx.x >> 3;        // 0..95
    const int bh  = xcd * 6 + (idx % 6);
    const int it  = 15 - (idx / 6);
    const int i0  = it * 128;

    const unsigned short* qb = Q    + (size_t)bh * TSEQ * HD;
    const unsigned short* kb = Kmat + (size_t)bh * TSEQ * HD;
    const unsigned short* vb = Vt   + (size_t)bh * HD * TSEQ;

    bf16x8 qf[2][2];
#pragma unroll
    for (int si = 0; si < 2; si++)
#pragma unroll
        for (int ks = 0; ks < 2; ks++)
            qf[si][ks] = *(const bf16x8*)(qb +
                (size_t)(i0 + wave * 32 + si * 16 + m16) * HD + ks * 32 + q4 * 8);

    f32x4 oacc[2][4];
#pragma unroll
    for (int si = 0; si < 2; si++)
#pragma unroll
        for (int dn = 0; dn < 4; dn++) oacc[si][dn] = f32x4{0.f, 0.f, 0.f, 0.f};

    // K frag read bases (u16): row*64 + swz*8; row = kk*32 + o*4 + q8*8 + m3
    const int fr  = ((q8 & 1) << 2) | m3;       // f(row) for this lane's rows
    const int kx0 = (q4 ^ fr) * 8;              // ks=0
    const int kx1 = kx0 ^ 32;                   // ks=1 (bit2 of ch flips)
    const int krb = (q8 * 8 + m3) * 64;

    for (int jt = 0; jt <= it; jt++) {
        const int j0 = jt * 128;
        // ---- stage K (128x64) and V^T (64x128), 3-bit XOR swizzled ----
#pragma unroll
        for (int cc = 0; cc < 4; cc++) {
            int cs = wave * 4 + cc;
            {   // K: chunk I = cs*64 + lane; row = I>>3, swz = I&7
                int rowK = cs * 8 + (lane >> 3);
                int chK  = (lane & 7) ^ ((((rowK >> 3) & 1) << 2) | (rowK & 3));
                gl_lds16(kb + (size_t)(j0 + rowK) * HD + chK * 8, &S[LDSK] + cs * 512);
            }
            {   // V: chunk I = cs*64 + lane; d = I>>4, swz = I&15
                int dV  = cs * 4 + (lane >> 4);
                int chV = (m16 & 8) | ((m16 ^ dV) & 7);
                gl_lds16(vb + (size_t)dV * TSEQ + j0 + chV * 8, &S[LDSV] + cs * 512);
            }
        }
        __syncthreads();

        const bool diag = (jt == it);
#pragma unroll
        for (int kk = 0; kk < 4; kk++) {
            const int kb0 = kk * 2048 + krb;
            bf16x8 kf_e0 = *(const bf16x8*)(&S[LDSK] + kb0 + kx0);
            bf16x8 kf_e1 = *(const bf16x8*)(&S[LDSK] + kb0 + kx1);
            bf16x8 kf_o0 = *(const bf16x8*)(&S[LDSK] + kb0 + 256 + kx0);
            bf16x8 kf_o1 = *(const bf16x8*)(&S[LDSK] + kb0 + 256 + kx1);

            f32x4 sacc[2][2];
#pragma unroll
            for (int o = 0; o < 2; o++)
#pragma unroll
                for (int si = 0; si < 2; si++) sacc[o][si] = f32x4{0.f, 0.f, 0.f, 0.f};
#pragma unroll
            for (int si = 0; si < 2; si++) {
                sacc[0][si] = mfma16(kf_e0, qf[si][0], sacc[0][si]);
                sacc[0][si] = mfma16(kf_e1, qf[si][1], sacc[0][si]);
                sacc[1][si] = mfma16(kf_o0, qf[si][0], sacc[1][si]);
                sacc[1][si] = mfma16(kf_o1, qf[si][1], sacc[1][si]);
            }

            unsigned int pk[2][2][2];
#pragma unroll
            for (int o = 0; o < 2; o++)
#pragma unroll
                for (int si = 0; si < 2; si++) {
                    f32x4 v = sacc[o][si];
                    if (diag) {
#pragma unroll
                        for (int r = 0; r < 4; r++) {
                            int gj = kk * 32 + q4 * 8 + o * 4 + r;
                            int gi = wave * 32 + si * 16 + m16;
                            if (gj > gi) v[r] = 0.f;
                        }
                    }
#pragma unroll
                    for (int r = 0; r < 4; r++) v[r] = fmaxf(v[r], 0.f);
                    pk[o][si][0] = pkbf(v[0], v[1]);
                    pk[o][si][1] = pkbf(v[2], v[3]);
                }

#pragma unroll
            for (int dn = 0; dn < 4; dn++) {
                int vsw = ((kk * 4 + q4) ^ (m16 & 7)) * 8;
                bf16x8 vf = *(const bf16x8*)(&S[LDSV] + (dn * 16 + m16) * 128 + vsw);
#pragma unroll
                for (int si = 0; si < 2; si++) {
                    union { bf16x8 v; unsigned int u[4]; } af;
                    af.u[0] = pk[0][si][0];
                    af.u[1] = pk[0][si][1];
                    af.u[2] = pk[1][si][0];
                    af.u[3] = pk[1][si][1];
                    oacc[si][dn] = mfma16(af.v, vf, oacc[si][dn]);
                }
            }
        }
        __syncthreads();
    }

    const int b = bh / NHEAD, h = bh % NHEAD;
#pragma unroll
    for (int si = 0; si < 2; si++) {
        int ri = i0 + wave * 32 + si * 16 + q4 * 4;
#pragma unroll
        for (int dn = 0; dn < 4; dn++) {
            int d = dn * 16 + m16;
#pragma unroll
            for (int r = 0; r < 4; r++) {
                Out[((size_t)b * TSEQ + ri + r) * CDIM + h * HD + d] = oacc[si][dn][r];
            }
        }
    }
}

// ---------------- launch ----------------
extern "C" void kernel_launch(void* const* d_in, const int* in_sizes, int n_in,
                              void* d_out, int out_size, void* d_ws, size_t ws_size,
                              hipStream_t stream) {
    const float* X    = (const float*)d_in[0];
    const float* W    = (const float*)d_in[1];
    const float* Bias = (const float*)d_in[2];
    float* out = (float*)d_out;

    unsigned short* Xb = (unsigned short*)d_ws;
    unsigned short* Wt = Xb + (size_t)MROWS * CDIM;
    unsigned short* Q  = Wt + (size_t)NQKV * CDIM;
    unsigned short* Km = Q  + (size_t)BHTOT * TSEQ * HD;
    unsigned short* Vt = Km + (size_t)BHTOT * TSEQ * HD;

    hipLaunchKernelGGL(convert_x, dim3((MROWS * CDIM) / 1024), dim3(256), 0, stream, X, Xb);
    hipLaunchKernelGGL(transpose_w, dim3(NQKV / 64, CDIM / 64), dim3(256), 0, stream, W, Wt);
    hipLaunchKernelGGL(qkv_gemm, dim3(NQKV / BN, MROWS / BM), dim3(256), 0, stream,
                       Xb, Wt, Bias, Q, Km, Vt);
    hipLaunchKernelGGL(attn, dim3(BHTOT * 16), dim3(256), 0, stream, Q, Km, Vt, out);
}